// Round 4
// baseline (23739.133 us; speedup 1.0000x reference)
//
#include <hip/hip_runtime.h>
#include <hip/hip_bf16.h>
#include <hip/hip_cooperative_groups.h>
#include <math.h>

namespace cg = cooperative_groups;

// Problem constants
#define BB   64      // batch
#define TT   512     // time steps
#define UU   350     // units per direction
#define GG   1050    // 3*UU gate columns
#define DCH  50
#define DWD  300
#define DIN  350     // DCH + DWD
#define CT   64      // time-chunk for xg staging
#define NCH  8       // TT / CT

// ---------------- ws layout (bytes) ----------------
// hbuf : [2 buf][2 dir][350 u][64 b] f32          = 358,400 B
// WhT  : [2 dir][1050 g][350 u] f32               = 2,940,000 B
// xg   : [2 dir][64 tloc][1050 g][64 b] f32       = 34,406,400 B
#define HBUF_OFF 0
#define HBUF_BYTES (2*2*UU*BB*4)
#define WHT_OFF  HBUF_BYTES
#define WHT_BYTES (2*GG*UU*4)
#define XG_OFF   3298560   // 256B-aligned past HBUF+WHT
#define XG_BYTES (2*CT*GG*BB*4)

// Transpose Wh -> WhT[dir][g][u] so the step kernel's weight reads are
// wave-uniform contiguous (scalar-load friendly).
__global__ __launch_bounds__(256) void wht_kernel(
    const float* __restrict__ Whf, const float* __restrict__ Whb,
    float* __restrict__ WhT)
{
    int idx = blockIdx.x * 256 + threadIdx.x;
    if (idx >= 2 * UU * GG) return;
    int dir = idx / (UU * GG);
    int r   = idx % (UU * GG);
    int u   = r / GG;
    int g   = r % GG;                 // consecutive lanes -> consecutive g: coalesced read
    const float* src = dir ? Whb : Whf;
    WhT[((size_t)dir * GG + g) * UU + u] = src[u * GG + g];
}

// xg GEMM for one time-chunk: xg[dir][tloc][g][b] = sum_k x[b,t,k]*Wx[k,g] + b0[g]
// 64g x 64b tile per block, K staged in 16-slabs through LDS.
__global__ __launch_bounds__(256) void xg_gemm_kernel(
    const float* __restrict__ ce, const float* __restrict__ we,
    const float* __restrict__ Wxf, const float* __restrict__ Wxb,
    const float* __restrict__ bf,  const float* __restrict__ bb,
    float* __restrict__ xg, int c)
{
    const int dir   = blockIdx.z;
    const int tloc  = blockIdx.y;
    const int gbase = blockIdx.x * 64;
    const int t     = dir ? (448 - c * CT + tloc) : (c * CT + tloc);
    const float* __restrict__ Wx   = dir ? Wxb : Wxf;
    const float* __restrict__ bias = dir ? bb  : bf;

    __shared__ float xs[16][68];   // [kk][b], padded to kill bank conflicts
    __shared__ float wsh[16][68];  // [kk][g]

    const int tid = threadIdx.x;
    const int b0 = (tid & 15) * 4;
    const int g0 = (tid >> 4) * 4;
    float acc[4][4] = {};          // [gi][bi]

    for (int k0 = 0; k0 < DIN; k0 += 16) {
        #pragma unroll
        for (int j = 0; j < 4; ++j) {
            int e = j * 256 + tid;
            int bbi = e >> 4, kk = e & 15;
            int k = k0 + kk;
            float v = 0.f;
            if (k < DIN)
                v = (k < DCH) ? ce[((size_t)bbi * TT + t) * DCH + k]
                              : we[((size_t)bbi * TT + t) * DWD + (k - DCH)];
            xs[kk][bbi] = v;
        }
        #pragma unroll
        for (int j = 0; j < 4; ++j) {
            int e = j * 256 + tid;
            int kk = e >> 6, gg = e & 63;
            int k = k0 + kk, g = gbase + gg;
            float v = 0.f;
            if (k < DIN && g < GG) v = Wx[(size_t)k * GG + g];
            wsh[kk][gg] = v;
        }
        __syncthreads();
        #pragma unroll
        for (int kk = 0; kk < 16; ++kk) {
            float4 xa = *(const float4*)&xs[kk][b0];
            float4 wa = *(const float4*)&wsh[kk][g0];
            acc[0][0] = fmaf(wa.x, xa.x, acc[0][0]);
            acc[0][1] = fmaf(wa.x, xa.y, acc[0][1]);
            acc[0][2] = fmaf(wa.x, xa.z, acc[0][2]);
            acc[0][3] = fmaf(wa.x, xa.w, acc[0][3]);
            acc[1][0] = fmaf(wa.y, xa.x, acc[1][0]);
            acc[1][1] = fmaf(wa.y, xa.y, acc[1][1]);
            acc[1][2] = fmaf(wa.y, xa.z, acc[1][2]);
            acc[1][3] = fmaf(wa.y, xa.w, acc[1][3]);
            acc[2][0] = fmaf(wa.z, xa.x, acc[2][0]);
            acc[2][1] = fmaf(wa.z, xa.y, acc[2][1]);
            acc[2][2] = fmaf(wa.z, xa.z, acc[2][2]);
            acc[2][3] = fmaf(wa.z, xa.w, acc[2][3]);
            acc[3][0] = fmaf(wa.w, xa.x, acc[3][0]);
            acc[3][1] = fmaf(wa.w, xa.y, acc[3][1]);
            acc[3][2] = fmaf(wa.w, xa.z, acc[3][2]);
            acc[3][3] = fmaf(wa.w, xa.w, acc[3][3]);
        }
        __syncthreads();
    }
    float* outp = xg + (size_t)((dir * CT + tloc) * GG) * BB;
    #pragma unroll
    for (int i = 0; i < 4; ++i) {
        int g = gbase + g0 + i;
        if (g < GG) {
            float bv = bias[g];
            float4 v;
            v.x = acc[i][0] + bv; v.y = acc[i][1] + bv;
            v.z = acc[i][2] + bv; v.w = acc[i][3] + bv;
            *(float4*)&outp[(size_t)g * BB + b0] = v;
        }
    }
}

// Persistent recurrence kernel for one 64-step chunk. 88 blocks x 512 threads:
// wave w (0..7): dir = w>>2, unit up = blockIdx.x*4 + (w&3). Each wave computes
// its unit's three gates for all 64 batches (lane = batch). grid.sync() between
// steps replaces 64 kernel launches.
__global__ __launch_bounds__(512) void gru_chunk_kernel(
    const float* __restrict__ xg, const float* __restrict__ WhT,
    const float* __restrict__ bf, const float* __restrict__ bb,
    const int* __restrict__ seqlen, float* __restrict__ hbuf,
    float* __restrict__ hid, int c)
{
    cg::grid_group grid = cg::this_grid();

    const int b   = threadIdx.x & 63;
    const int w   = __builtin_amdgcn_readfirstlane((int)(threadIdx.x >> 6)); // 0..7, wave-uniform
    const int dir = w >> 2;
    const int up  = blockIdx.x * 4 + (w & 3);
    const bool act = (up < UU);
    const int slen = seqlen[b];

    const float* __restrict__ bias = dir ? bb : bf;   // [2,1050]; b1 at +1050
    const float* __restrict__ wz = WhT + ((size_t)dir * GG + (act ? up : 0)) * UU;
    const float* __restrict__ wr = WhT + ((size_t)dir * GG + UU + (act ? up : 0)) * UU;
    const float* __restrict__ wh = WhT + ((size_t)dir * GG + 2 * UU + (act ? up : 0)) * UU;
    const float bz = act ? bias[GG + up] : 0.f;
    const float br = act ? bias[GG + UU + up] : 0.f;
    const float bh = act ? bias[GG + 2 * UU + up] : 0.f;

    for (int sl = 0; sl < CT; ++sl) {
        const int s    = c * CT + sl;
        const int t    = dir ? (TT - 1 - s) : s;
        const int tloc = dir ? (CT - 1 - sl) : sl;

        const float* __restrict__ hR = hbuf + (size_t)(((s & 1) * 2) + dir) * (UU * BB);
        float* __restrict__       hW = hbuf + (size_t)((((s & 1) ^ 1) * 2) + dir) * (UU * BB);

        if (act) {
            float hz = bz, hr = br, hc = bh;
            #pragma unroll 10
            for (int u = 0; u < UU; ++u) {
                float hv = hR[u * BB + b];
                hz = fmaf(hv, wz[u], hz);
                hr = fmaf(hv, wr[u], hr);
                hc = fmaf(hv, wh[u], hc);
            }

            const float* xgp = xg + (size_t)((dir * CT + tloc) * GG) * BB;
            float xz = xgp[(size_t)(up)          * BB + b];
            float xr = xgp[(size_t)(up + UU)     * BB + b];
            float xh = xgp[(size_t)(up + 2 * UU) * BB + b];

            float z   = 1.f / (1.f + expf(-(xz + hz)));
            float r   = 1.f / (1.f + expf(-(xr + hr)));
            float cnd = tanhf(xh + r * hc);
            float hprev = hR[up * BB + b];
            float hnew  = z * hprev + (1.f - z) * cnd;
            bool  m     = (t < slen);
            hnew = m ? hnew : hprev;

            hW[up * BB + b] = hnew;
            hid[((size_t)b * TT + t) * 700 + dir * UU + up] = hnew;
        }

        if (sl != CT - 1) {          // last step: kernel boundary provides sync
            __threadfence();
            grid.sync();
        }
    }
}

// Final projections + 2-class softmax. One wave per (b,t) row.
__global__ __launch_bounds__(256) void proj_kernel(
    const float* __restrict__ Wz, const float* __restrict__ Wq,
    const float* __restrict__ hid, float* __restrict__ zT, float* __restrict__ zS)
{
    const int wave = threadIdx.x >> 6;
    const int lane = threadIdx.x & 63;
    const int row  = blockIdx.x * 4 + wave;     // row = b*T + t
    const float* hp = hid + (size_t)row * 700;
    float a0 = 0.f, a1 = 0.f, a2 = 0.f, a3 = 0.f;
    #pragma unroll
    for (int i = 0; i < 11; ++i) {
        int j = i * 64 + lane;
        if (j < 700) {
            float hv = hp[j];
            a0 = fmaf(hv, Wz[j], a0);
            a1 = fmaf(hv, Wz[700 + j], a1);
            a2 = fmaf(hv, Wq[j], a2);
            a3 = fmaf(hv, Wq[700 + j], a3);
        }
    }
    #pragma unroll
    for (int off = 32; off; off >>= 1) {
        a0 += __shfl_xor(a0, off, 64);
        a1 += __shfl_xor(a1, off, 64);
        a2 += __shfl_xor(a2, off, 64);
        a3 += __shfl_xor(a3, off, 64);
    }
    if (lane == 0) {
        float m1 = fmaxf(a0, a1);
        float e0 = expf(a0 - m1), e1 = expf(a1 - m1);
        float s1 = e0 + e1;
        zT[(size_t)row * 2]     = e0 / s1;
        zT[(size_t)row * 2 + 1] = e1 / s1;
        float m2 = fmaxf(a2, a3);
        float f0 = expf(a2 - m2), f1 = expf(a3 - m2);
        float s2 = f0 + f1;
        zS[(size_t)row * 2]     = f0 / s2;
        zS[(size_t)row * 2 + 1] = f1 / s2;
    }
}

extern "C" void kernel_launch(void* const* d_in, const int* in_sizes, int n_in,
                              void* d_out, int out_size, void* d_ws, size_t ws_size,
                              hipStream_t stream)
{
    (void)in_sizes; (void)n_in; (void)out_size; (void)ws_size;
    const float* ce  = (const float*)d_in[0];   // char_embedding [64,512,50]
    const float* we  = (const float*)d_in[1];   // word_embedding [64,512,300]
    const int*   sl  = (const int*)d_in[2];     // sequence_length [64]
    // d_in[3] = mask (bool) -- recomputed from sequence_length instead
    const float* Wz  = (const float*)d_in[4];   // [2,700]
    const float* Wq  = (const float*)d_in[5];   // [2,700]
    const float* Wxf = (const float*)d_in[6];   // [350,1050]
    const float* Whf = (const float*)d_in[7];   // [350,1050]
    const float* bf  = (const float*)d_in[8];   // [2,1050]
    const float* Wxb = (const float*)d_in[9];
    const float* Whb = (const float*)d_in[10];
    const float* bb  = (const float*)d_in[11];

    float* out = (float*)d_out;
    float* zT  = out;                       // [64,512,2]
    float* zS  = out + (size_t)BB * TT * 2; // [64,512,2]
    float* hid = out + (size_t)2 * BB * TT * 2; // [64,512,700]

    char* ws = (char*)d_ws;
    float* hbuf = (float*)(ws + HBUF_OFF);
    float* WhT  = (float*)(ws + WHT_OFF);
    float* xg   = (float*)(ws + XG_OFF);

    // zero initial hidden state (ws is poisoned before every launch)
    hipMemsetAsync(hbuf, 0, HBUF_BYTES, stream);
    wht_kernel<<<dim3((2 * UU * GG + 255) / 256), 256, 0, stream>>>(Whf, Whb, WhT);

    int cvals[NCH];
    for (int c = 0; c < NCH; ++c) {
        xg_gemm_kernel<<<dim3(17, CT, 2), 256, 0, stream>>>(ce, we, Wxf, Wxb, bf, bb, xg, c);
        cvals[c] = c;
        const float* xgc = xg;  // lvalues for kernelParams
        void* args[] = { (void*)&xgc, (void*)&WhT, (void*)&bf, (void*)&bb,
                         (void*)&sl, (void*)&hbuf, (void*)&hid, (void*)&cvals[c] };
        hipLaunchCooperativeKernel((const void*)gru_chunk_kernel,
                                   dim3(88), dim3(512), args, 0, stream);
    }
    proj_kernel<<<dim3(BB * TT / 4), 256, 0, stream>>>(Wz, Wq, hid, zT, zS);
}

// Round 9
// 8336.812 us; speedup vs baseline: 2.8475x; 2.8475x over previous
//
#include <hip/hip_runtime.h>
#include <hip/hip_bf16.h>
#include <math.h>

// Problem constants
#define BB   64      // batch
#define TT   512     // time steps
#define UU   350     // units per direction
#define GG   1050    // 3*UU gate columns
#define DCH  50
#define DWD  300
#define DIN  350     // DCH + DWD
#define CT   64      // time-chunk for xg staging
#define NCH  8       // TT / CT

// Recurrence decomposition: cluster = (dir, batch-group). 22 unit-slices
// of 16 units each cover 350 (2 pad). 4 batch-groups of 16. 176 blocks
// x 256 thr. Co-residency is GUARANTEED by cooperative launch (not assumed
// from capacity arithmetic) -> flag-based spin sync cannot deadlock.
#define NSLICE 22
#define UPB    16
#define NBG    4
#define BPG    16

// ---------------- ws layout (bytes) ----------------
// flags : [2 dir][4 bg][22 slice] int  (pad to 1024)
// WhT   : [2 dir][1050 g][352 u] f32 (row-padded to 352 for 16B align) = 2,956,800
// xg    : [2 dir][64 tloc][1050 g][64 b] f32 = 34,406,400
#define FLAGS_OFF 0
#define WHT_ROW   352
#define WHT_OFF   1024
#define WHT_BYTES (2*GG*WHT_ROW*4)
#define XG_OFF    (WHT_OFF + WHT_BYTES)   // 2,957,824 (16B aligned)

// Transpose Wh -> WhT[dir][g][u_in] with row stride 352 (zero-padded) so the
// recurrence reads weights as aligned float4 along u_in.
__global__ __launch_bounds__(256) void wht_kernel(
    const float* __restrict__ Whf, const float* __restrict__ Whb,
    float* __restrict__ WhT)
{
    int idx = blockIdx.x * 256 + threadIdx.x;
    if (idx >= 2 * WHT_ROW * GG) return;
    int dir = idx / (WHT_ROW * GG);
    int r   = idx % (WHT_ROW * GG);
    int u   = r / GG;                 // 0..351
    int g   = r % GG;                 // consecutive lanes -> consecutive g: coalesced read
    const float* src = dir ? Whb : Whf;
    float v = (u < UU) ? src[u * GG + g] : 0.f;
    WhT[((size_t)dir * GG + g) * WHT_ROW + u] = v;
}

// xg GEMM for one time-chunk: xg[dir][tloc][g][b] = sum_k x[b,t,k]*Wx[k,g] + b0[g]
__global__ __launch_bounds__(256) void xg_gemm_kernel(
    const float* __restrict__ ce, const float* __restrict__ we,
    const float* __restrict__ Wxf, const float* __restrict__ Wxb,
    const float* __restrict__ bf,  const float* __restrict__ bb,
    float* __restrict__ xg, int c)
{
    const int dir   = blockIdx.z;
    const int tloc  = blockIdx.y;
    const int gbase = blockIdx.x * 64;
    const int t     = dir ? (448 - c * CT + tloc) : (c * CT + tloc);
    const float* __restrict__ Wx   = dir ? Wxb : Wxf;
    const float* __restrict__ bias = dir ? bb  : bf;

    __shared__ float xs[16][68];
    __shared__ float wsh[16][68];

    const int tid = threadIdx.x;
    const int b0 = (tid & 15) * 4;
    const int g0 = (tid >> 4) * 4;
    float acc[4][4] = {};

    for (int k0 = 0; k0 < DIN; k0 += 16) {
        #pragma unroll
        for (int j = 0; j < 4; ++j) {
            int e = j * 256 + tid;
            int bbi = e >> 4, kk = e & 15;
            int k = k0 + kk;
            float v = 0.f;
            if (k < DIN)
                v = (k < DCH) ? ce[((size_t)bbi * TT + t) * DCH + k]
                              : we[((size_t)bbi * TT + t) * DWD + (k - DCH)];
            xs[kk][bbi] = v;
        }
        #pragma unroll
        for (int j = 0; j < 4; ++j) {
            int e = j * 256 + tid;
            int kk = e >> 6, gg = e & 63;
            int k = k0 + kk, g = gbase + gg;
            float v = 0.f;
            if (k < DIN && g < GG) v = Wx[(size_t)k * GG + g];
            wsh[kk][gg] = v;
        }
        __syncthreads();
        #pragma unroll
        for (int kk = 0; kk < 16; ++kk) {
            float4 xa = *(const float4*)&xs[kk][b0];
            float4 wa = *(const float4*)&wsh[kk][g0];
            acc[0][0] = fmaf(wa.x, xa.x, acc[0][0]);
            acc[0][1] = fmaf(wa.x, xa.y, acc[0][1]);
            acc[0][2] = fmaf(wa.x, xa.z, acc[0][2]);
            acc[0][3] = fmaf(wa.x, xa.w, acc[0][3]);
            acc[1][0] = fmaf(wa.y, xa.x, acc[1][0]);
            acc[1][1] = fmaf(wa.y, xa.y, acc[1][1]);
            acc[1][2] = fmaf(wa.y, xa.z, acc[1][2]);
            acc[1][3] = fmaf(wa.y, xa.w, acc[1][3]);
            acc[2][0] = fmaf(wa.z, xa.x, acc[2][0]);
            acc[2][1] = fmaf(wa.z, xa.y, acc[2][1]);
            acc[2][2] = fmaf(wa.z, xa.z, acc[2][2]);
            acc[2][3] = fmaf(wa.z, xa.w, acc[2][3]);
            acc[3][0] = fmaf(wa.w, xa.x, acc[3][0]);
            acc[3][1] = fmaf(wa.w, xa.y, acc[3][1]);
            acc[3][2] = fmaf(wa.w, xa.z, acc[3][2]);
            acc[3][3] = fmaf(wa.w, xa.w, acc[3][3]);
        }
        __syncthreads();
    }
    float* outp = xg + (size_t)((dir * CT + tloc) * GG) * BB;
    #pragma unroll
    for (int i = 0; i < 4; ++i) {
        int g = gbase + g0 + i;
        if (g < GG) {
            float bv = bias[g];
            float4 v;
            v.x = acc[i][0] + bv; v.y = acc[i][1] + bv;
            v.z = acc[i][2] + bv; v.w = acc[i][3] + bv;
            *(float4*)&outp[(size_t)g * BB + b0] = v;
        }
    }
}

// Recurrence for one 64-step chunk. Block = (uslice, bgroup, dir), 256 thr.
// Lane layout: wave wv (0..3), slot (0..3), b16 (0..15): unit = us*16+wv*4+slot,
// batch = bg*16+b16. h state lives directly in hid (d_out) in final layout;
// cross-block h/flag traffic uses relaxed AGENT-scope atomics (sc0/sc1,
// coherent per-access, NO L2 writeback/invalidate ops anywhere in the loop).
// Sync = per-cluster flags: 22 blocks of (dir,bg) spin on each other only.
//
// RACE FIX (r5->r6): before the barrier that precedes the flag store, EVERY
// thread drains its own vmem with s_waitcnt vmcnt(0). The h stores carry
// agent scope (sc0/sc1 write-through), so vmcnt(0) => device-visible.
// HANG FIX (r6->r7): launched via hipLaunchCooperativeKernel so all 176
// blocks are guaranteed co-resident (plain launch only makes this likely).
__global__ __launch_bounds__(256) void gru_chunk_kernel(
    const float* __restrict__ xg, const float* __restrict__ WhT,
    const float* __restrict__ bf, const float* __restrict__ bb,
    const int* __restrict__ seqlen, int* __restrict__ flags,
    float* __restrict__ hid, int c)
{
    __shared__ float h_lds[BPG][356];   // [b16][k], stride 356 (16B-aligned rows)

    const int tid  = threadIdx.x;
    const int lane = tid & 63;
    const int wv   = tid >> 6;
    const int slot = (lane >> 4) & 3;
    const int b16  = lane & 15;
    const int us   = blockIdx.x;
    const int bg   = blockIdx.y;
    const int dir  = blockIdx.z;
    const int u    = us * UPB + wv * 4 + slot;
    const int b    = bg * BPG + b16;
    const bool act = (u < UU);
    const int uc   = act ? u : 0;
    const int slen = seqlen[b];

    const float* __restrict__ bias = dir ? bb : bf;
    const float* __restrict__ wzp = WhT + (size_t)(dir * GG + uc)          * WHT_ROW;
    const float* __restrict__ wrp = WhT + (size_t)(dir * GG + UU + uc)     * WHT_ROW;
    const float* __restrict__ whp = WhT + (size_t)(dir * GG + 2 * UU + uc) * WHT_ROW;
    const float b1z = bias[GG + uc];
    const float b1r = bias[GG + UU + uc];
    const float b1h = bias[GG + 2 * UU + uc];
    int* myflags = flags + (dir * NBG + bg) * NSLICE;

    // staging role: 16 threads per batch-row
    const int sb = tid >> 4;           // 0..15 : batch row to stage
    const int sk = (tid & 15) * 2;     // 0,2,..30 : k-pair within 32-chunk

    for (int sl = 0; sl < CT; ++sl) {
        const int s = c * CT + sl;
        const int t = dir ? (TT - 1 - s) : s;

        if (s > 0) {
            // wave-level poll: all 22 slices of this cluster must have h(s-1)
            for (;;) {
                int ok = 1;
                if (lane < NSLICE)
                    ok = (__hip_atomic_load(&myflags[lane], __ATOMIC_RELAXED,
                                            __HIP_MEMORY_SCOPE_AGENT) >= s);
                if (__all(ok)) break;
                __builtin_amdgcn_s_sleep(2);
            }
            // stage h(s-1) for our 16 batches into LDS (coherent 8B loads)
            const int tp = dir ? (t + 1) : (t - 1);
            const float* hrow = hid + ((size_t)(bg * BPG + sb) * TT + tp) * 700 + dir * UU;
            #pragma unroll
            for (int j = 0; j < 11; ++j) {
                int k0 = sk + 32 * j;
                if (k0 < UU) {
                    unsigned long long v = __hip_atomic_load(
                        (unsigned long long*)(hrow + k0),
                        __ATOMIC_RELAXED, __HIP_MEMORY_SCOPE_AGENT);
                    h_lds[sb][k0]     = __uint_as_float((unsigned)v);
                    h_lds[sb][k0 + 1] = __uint_as_float((unsigned)(v >> 32));
                }
            }
        }
        __syncthreads();

        float hz = b1z, hr = b1r, hcd = b1h;
        float hprev = 0.f;
        if (s > 0) {
            const float* hl = &h_lds[b16][0];
            #pragma unroll 3
            for (int k = 0; k < 348; k += 4) {
                float4 h4  = *(const float4*)(hl + k);
                float4 wz4 = *(const float4*)(wzp + k);
                float4 wr4 = *(const float4*)(wrp + k);
                float4 wh4 = *(const float4*)(whp + k);
                hz  = fmaf(h4.x, wz4.x, hz);
                hz  = fmaf(h4.y, wz4.y, hz);
                hz  = fmaf(h4.z, wz4.z, hz);
                hz  = fmaf(h4.w, wz4.w, hz);
                hr  = fmaf(h4.x, wr4.x, hr);
                hr  = fmaf(h4.y, wr4.y, hr);
                hr  = fmaf(h4.z, wr4.z, hr);
                hr  = fmaf(h4.w, wr4.w, hr);
                hcd = fmaf(h4.x, wh4.x, hcd);
                hcd = fmaf(h4.y, wh4.y, hcd);
                hcd = fmaf(h4.z, wh4.z, hcd);
                hcd = fmaf(h4.w, wh4.w, hcd);
            }
            float2 ht = *(const float2*)(hl + 348);
            hz  = fmaf(ht.x, wzp[348], hz);   hz  = fmaf(ht.y, wzp[349], hz);
            hr  = fmaf(ht.x, wrp[348], hr);   hr  = fmaf(ht.y, wrp[349], hr);
            hcd = fmaf(ht.x, whp[348], hcd);  hcd = fmaf(ht.y, whp[349], hcd);
            hprev = hl[uc];
        }

        // input gates (precomputed) + nonlinearities
        const int tloc = dir ? (CT - 1 - sl) : sl;
        const float* xgp = xg + (size_t)((dir * CT + tloc) * GG) * BB;
        float xz = 0.f, xr = 0.f, xh = 0.f;
        if (act) {
            xz = xgp[(size_t)uc * BB + b];
            xr = xgp[(size_t)(uc + UU) * BB + b];
            xh = xgp[(size_t)(uc + 2 * UU) * BB + b];
        }
        float z   = 1.f / (1.f + expf(-(xz + hz)));
        float r   = 1.f / (1.f + expf(-(xr + hr)));
        float cnd = tanhf(xh + r * hcd);
        float hnew = z * hprev + (1.f - z) * cnd;
        hnew = (t < slen) ? hnew : hprev;

        if (act)
            __hip_atomic_store(&hid[((size_t)b * TT + t) * 700 + dir * UU + u], hnew,
                               __ATOMIC_RELAXED, __HIP_MEMORY_SCOPE_AGENT);

        // Drain THIS thread's stores to the coherence point, then barrier.
        // Every thread executes this, so after the barrier ALL h stores of the
        // block are device-visible; only then does tid0 publish the flag.
        asm volatile("s_waitcnt vmcnt(0)" ::: "memory");
        __syncthreads();
        if (tid == 0)
            __hip_atomic_store(&myflags[us], s + 1,
                               __ATOMIC_RELAXED, __HIP_MEMORY_SCOPE_AGENT);
    }
}

// Final projections + 2-class softmax. One wave per (b,t) row.
__global__ __launch_bounds__(256) void proj_kernel(
    const float* __restrict__ Wz, const float* __restrict__ Wq,
    const float* __restrict__ hid, float* __restrict__ zT, float* __restrict__ zS)
{
    const int wave = threadIdx.x >> 6;
    const int lane = threadIdx.x & 63;
    const int row  = blockIdx.x * 4 + wave;
    const float* hp = hid + (size_t)row * 700;
    float a0 = 0.f, a1 = 0.f, a2 = 0.f, a3 = 0.f;
    #pragma unroll
    for (int i = 0; i < 11; ++i) {
        int j = i * 64 + lane;
        if (j < 700) {
            float hv = hp[j];
            a0 = fmaf(hv, Wz[j], a0);
            a1 = fmaf(hv, Wz[700 + j], a1);
            a2 = fmaf(hv, Wq[j], a2);
            a3 = fmaf(hv, Wq[700 + j], a3);
        }
    }
    #pragma unroll
    for (int off = 32; off; off >>= 1) {
        a0 += __shfl_xor(a0, off, 64);
        a1 += __shfl_xor(a1, off, 64);
        a2 += __shfl_xor(a2, off, 64);
        a3 += __shfl_xor(a3, off, 64);
    }
    if (lane == 0) {
        float m1 = fmaxf(a0, a1);
        float e0 = expf(a0 - m1), e1 = expf(a1 - m1);
        float s1 = e0 + e1;
        zT[(size_t)row * 2]     = e0 / s1;
        zT[(size_t)row * 2 + 1] = e1 / s1;
        float m2 = fmaxf(a2, a3);
        float f0 = expf(a2 - m2), f1 = expf(a3 - m2);
        float s2 = f0 + f1;
        zS[(size_t)row * 2]     = f0 / s2;
        zS[(size_t)row * 2 + 1] = f1 / s2;
    }
}

extern "C" void kernel_launch(void* const* d_in, const int* in_sizes, int n_in,
                              void* d_out, int out_size, void* d_ws, size_t ws_size,
                              hipStream_t stream)
{
    (void)in_sizes; (void)n_in; (void)out_size; (void)ws_size;
    const float* ce  = (const float*)d_in[0];   // char_embedding [64,512,50]
    const float* we  = (const float*)d_in[1];   // word_embedding [64,512,300]
    const int*   sl  = (const int*)d_in[2];     // sequence_length [64]
    // d_in[3] = mask (bool) -- recomputed from sequence_length
    const float* Wz  = (const float*)d_in[4];   // [2,700]
    const float* Wq  = (const float*)d_in[5];   // [2,700]
    const float* Wxf = (const float*)d_in[6];   // [350,1050]
    const float* Whf = (const float*)d_in[7];   // [350,1050]
    const float* bf  = (const float*)d_in[8];   // [2,1050]
    const float* Wxb = (const float*)d_in[9];
    const float* Whb = (const float*)d_in[10];
    const float* bb  = (const float*)d_in[11];

    float* out = (float*)d_out;
    float* zT  = out;
    float* zS  = out + (size_t)BB * TT * 2;
    float* hid = out + (size_t)2 * BB * TT * 2;   // [64,512,700] — also the h state

    char* ws = (char*)d_ws;
    int*   flags = (int*)(ws + FLAGS_OFF);
    float* WhT   = (float*)(ws + WHT_OFF);
    float* xg    = (float*)(ws + XG_OFF);

    hipMemsetAsync(flags, 0, 1024, stream);   // ws re-poisoned each call
    wht_kernel<<<dim3((2 * WHT_ROW * GG + 255) / 256), 256, 0, stream>>>(Whf, Whb, WhT);

    int cvals[NCH];
    for (int c = 0; c < NCH; ++c) {
        xg_gemm_kernel<<<dim3(17, CT, 2), 256, 0, stream>>>(ce, we, Wxf, Wxb, bf, bb, xg, c);
        cvals[c] = c;
        const float* xgc = xg;
        const float* WhTc = WhT;
        void* args[] = { (void*)&xgc, (void*)&WhTc, (void*)&bf, (void*)&bb,
                         (void*)&sl, (void*)&flags, (void*)&hid, (void*)&cvals[c] };
        hipLaunchCooperativeKernel((const void*)gru_chunk_kernel,
                                   dim3(NSLICE, NBG, 2), dim3(256), args, 0, stream);
    }
    proj_kernel<<<dim3(BB * TT / 4), 256, 0, stream>>>(Wz, Wq, hid, zT, zS);
}